// Round 1
// baseline (2068.280 us; speedup 1.0000x reference)
//
#include <hip/hip_runtime.h>
#include <math.h>

#define Bb 32
#define Ss 256
#define Dd 64
#define Hh 512
#define G4 (4*Hh)   // 2048 gate rows

// ---------------------------------------------------------------------------
// init: h0 = hidden_0 @ W_hid^T + b_hid  -> out_h0, hbuf0, cbuf ; zero Abuf
// grid: 256 x 256 (65536 threads; Abuf has 65536 elements)
// ---------------------------------------------------------------------------
__global__ __launch_bounds__(256) void init_kernel(
    const float* __restrict__ hidden0,  // [B, D]
    const float* __restrict__ W_hid,    // [H, D]
    const float* __restrict__ b_hid,    // [H]
    float* __restrict__ out_h0,         // [B*H] (d_out + B*S*H)
    float* __restrict__ hbuf0,          // [B*H]
    float* __restrict__ cbuf,           // [B*H]
    float* __restrict__ Abuf)           // [G4*B] running x@W_ih accumulator
{
    int gid = blockIdx.x * 256 + threadIdx.x;
    Abuf[gid] = 0.0f;                   // gid < 65536 == G4*B exactly
    if (gid < Bb * Hh) {
        int b = gid >> 9;               // /H
        int h = gid & (Hh - 1);
        float acc = b_hid[h];
        const float* hv = hidden0 + b * Dd;
        const float* wv = W_hid + h * Dd;
        #pragma unroll 8
        for (int d = 0; d < Dd; ++d) acc += hv[d] * wv[d];
        out_h0[gid] = acc;
        hbuf0[gid]  = acc;   // h_0
        cbuf[gid]   = acc;   // c_0  (reference uses h0 for both)
    }
}

// ---------------------------------------------------------------------------
// One LSTM step. Grid: 256 blocks x 256 threads.
// Block owns j-pair {J, J+1} -> 8 gate rows: row_global(rl) = (rl>>1)*H + J + (rl&1)
// Thread (rl, b) computes one gate pre-activation for one batch element.
// ---------------------------------------------------------------------------
__global__ __launch_bounds__(256) void step_kernel(
    int t,
    const float* __restrict__ x,      // [B, S, D]
    const float* __restrict__ W_ih,   // [G4, S*D]
    const float* __restrict__ W_hh,   // [G4, H]
    const float* __restrict__ b_ih,   // [G4]
    const float* __restrict__ b_hh,   // [G4]
    const float* __restrict__ h_in,   // [B*H]
    float* __restrict__ h_out,        // [B*H]
    float* __restrict__ cbuf,         // [B*H]
    float* __restrict__ Abuf,         // [G4*B], laid out (blockIdx*8+rl)*32+b
    float* __restrict__ out)          // [B, S, H]
{
    __shared__ float hs[Bb][Hh + 4];   // +4 pad: breaks 32-way bank conflict
    __shared__ float wshh[8][Hh];      // broadcast reads, no pad needed
    __shared__ float xs[Bb][Dd + 4];
    __shared__ float wih_s[8][Dd];
    __shared__ float gs[8][32];

    const int tid   = threadIdx.x;
    const int Jbase = blockIdx.x * 2;

    // ---- stage h (16384 f32, float4-vectorized, coalesced) ----
    #pragma unroll
    for (int i = 0; i < 16; ++i) {
        int e = tid + i * 256;                 // 0..4095 float4s
        int b = e >> 7;
        int k = (e & 127) * 4;
        *reinterpret_cast<float4*>(&hs[b][k]) =
            *reinterpret_cast<const float4*>(&h_in[e * 4]);
    }
    // ---- stage W_hh slice (8 rows x 512) ----
    #pragma unroll
    for (int i = 0; i < 4; ++i) {
        int e = tid + i * 256;                 // 0..1023 float4s
        int r = e >> 7;
        int k = (e & 127) * 4;
        int rg = (r >> 1) * Hh + Jbase + (r & 1);
        *reinterpret_cast<float4*>(&wshh[r][k]) =
            *reinterpret_cast<const float4*>(&W_hh[rg * Hh + k]);
    }
    // ---- stage x_t (32 x 64) ----
    #pragma unroll
    for (int i = 0; i < 2; ++i) {
        int e = tid + i * 256;                 // 0..511 float4s
        int b = e >> 4;
        int d = (e & 15) * 4;
        *reinterpret_cast<float4*>(&xs[b][d]) =
            *reinterpret_cast<const float4*>(&x[(b * Ss + t) * Dd + d]);
    }
    // ---- stage W_ih slice (8 rows x 64 at column block t) ----
    if (tid < 128) {
        int r  = tid >> 4;
        int dd = (tid & 15) * 4;
        int rg = (r >> 1) * Hh + Jbase + (r & 1);
        *reinterpret_cast<float4*>(&wih_s[r][dd]) =
            *reinterpret_cast<const float4*>(&W_ih[(size_t)rg * (Ss * Dd) + (size_t)t * Dd + dd]);
    }
    __syncthreads();

    const int b  = tid & 31;
    const int rl = tid >> 5;                       // 0..7
    const int rg = (rl >> 1) * Hh + Jbase + (rl & 1);

    // ---- A += x_t . W_ih_row ----
    float adot = 0.0f;
    {
        const float4* xv = reinterpret_cast<const float4*>(&xs[b][0]);
        const float4* wv = reinterpret_cast<const float4*>(&wih_s[rl][0]);
        #pragma unroll
        for (int kk = 0; kk < 16; ++kk) {
            float4 a = xv[kk], w = wv[kk];
            adot += a.x * w.x + a.y * w.y + a.z * w.z + a.w * w.w;
        }
    }
    const int aidx = (blockIdx.x * 8 + rl) * 32 + b;
    float A = Abuf[aidx] + adot;
    Abuf[aidx] = A;

    // ---- gate = A + h . W_hh_row + biases ----
    float acc0 = 0.f, acc1 = 0.f, acc2 = 0.f, acc3 = 0.f;
    {
        const float4* hv = reinterpret_cast<const float4*>(&hs[b][0]);
        const float4* wv = reinterpret_cast<const float4*>(&wshh[rl][0]);
        #pragma unroll 16
        for (int kk = 0; kk < 128; ++kk) {
            float4 h4 = hv[kk], w4 = wv[kk];
            acc0 += h4.x * w4.x;
            acc1 += h4.y * w4.y;
            acc2 += h4.z * w4.z;
            acc3 += h4.w * w4.w;
        }
    }
    float gate = A + (acc0 + acc1) + (acc2 + acc3) + b_ih[rg] + b_hh[rg];
    gs[rl][b] = gate;
    __syncthreads();

    // ---- gate exchange + state update: threads rl<2 own (j2=rl, b) ----
    if (rl < 2) {
        const int j2 = rl;
        const int j  = Jbase + j2;
        float ip = gs[0 * 2 + j2][b];
        float fp = gs[1 * 2 + j2][b];
        float gp = gs[2 * 2 + j2][b];
        float op = gs[3 * 2 + j2][b];
        float ig = 1.0f / (1.0f + expf(-ip));
        float fg = 1.0f / (1.0f + expf(-fp));
        float gg = tanhf(gp);
        float og = 1.0f / (1.0f + expf(-op));
        const int cidx = b * Hh + j;
        float c_new = fg * cbuf[cidx] + ig * gg;
        cbuf[cidx] = c_new;
        float h_new = og * tanhf(c_new);
        h_out[cidx] = h_new;
        out[((size_t)b * Ss + t) * Hh + j] = fmaxf(h_new, 0.0f);
    }
}

// ---------------------------------------------------------------------------
extern "C" void kernel_launch(void* const* d_in, const int* in_sizes, int n_in,
                              void* d_out, int out_size, void* d_ws, size_t ws_size,
                              hipStream_t stream) {
    const float* x       = (const float*)d_in[0];
    const float* hidden0 = (const float*)d_in[1];
    const float* W_hid   = (const float*)d_in[2];
    const float* b_hid   = (const float*)d_in[3];
    const float* W_ih    = (const float*)d_in[4];
    const float* W_hh    = (const float*)d_in[5];
    const float* b_ih    = (const float*)d_in[6];
    const float* b_hh    = (const float*)d_in[7];

    float* out    = (float*)d_out;
    float* out_h0 = out + (size_t)Bb * Ss * Hh;

    float* ws    = (float*)d_ws;
    float* hbuf0 = ws;                  // 16384
    float* hbuf1 = ws + 16384;          // 16384
    float* cbuf  = ws + 32768;          // 16384
    float* Abuf  = ws + 49152;          // 65536

    init_kernel<<<256, 256, 0, stream>>>(hidden0, W_hid, b_hid, out_h0, hbuf0, cbuf, Abuf);

    for (int t = 0; t < Ss; ++t) {
        const float* hin = (t & 1) ? hbuf1 : hbuf0;
        float*       hout = (t & 1) ? hbuf0 : hbuf1;
        step_kernel<<<256, 256, 0, stream>>>(t, x, W_ih, W_hh, b_ih, b_hh,
                                             hin, hout, cbuf, Abuf, out);
    }
}

// Round 2
// 1291.905 us; speedup vs baseline: 1.6010x; 1.6010x over previous
//
#include <hip/hip_runtime.h>
#include <math.h>

#define NBLK 64

typedef __attribute__((ext_vector_type(8))) short short8;
typedef __attribute__((ext_vector_type(8))) _Float16 f16x8;
typedef __attribute__((ext_vector_type(4))) float f32x4;

__device__ __forceinline__ void split_f16(float f, unsigned short& h, unsigned short& l){
  _Float16 hh = (_Float16)f;
  _Float16 ll = (_Float16)(f - (float)hh);
  h = __builtin_bit_cast(unsigned short, hh);
  l = __builtin_bit_cast(unsigned short, ll);
}

__global__ __launch_bounds__(256) void lstm_persist(
    const float* __restrict__ x,
    const float* __restrict__ hidden0,
    const float* __restrict__ W_hid,
    const float* __restrict__ b_hid,
    const float* __restrict__ W_ih,
    const float* __restrict__ W_hh,
    const float* __restrict__ b_ih,
    const float* __restrict__ b_hh,
    float* __restrict__ out,
    float* __restrict__ out_h0,
    unsigned* __restrict__ ctr,
    float* __restrict__ h0f,
    unsigned short* __restrict__ hf_hi,   // [2][32][512] f16 bits
    unsigned short* __restrict__ hf_lo,
    unsigned short* __restrict__ xhi,     // [32][256][64] f16 bits
    unsigned short* __restrict__ xlo)
{
  __shared__ unsigned short hs_hi[16384];  // 32 KB, 16B units, XOR-swizzled
  __shared__ unsigned short hs_lo[16384];
  __shared__ float gs[32][33];

  const int tid  = threadIdx.x;
  const int bid  = blockIdx.x;
  const int lane = tid & 63;
  const int wid  = tid >> 6;   // 0..3
  const int r    = wid >> 1;   // row-tile: 0 = i/f rows, 1 = g/o rows
  const int cc   = wid & 1;    // col-tile (batch half)
  const int m    = lane & 15;
  const int g    = lane >> 4;
  const int J0   = bid * 8;    // this block owns hidden columns J0..J0+7
  const int gid  = bid * 256 + tid;

  // ---------------- init: h0 = hidden0 @ W_hid^T + b_hid ----------------
  {
    int b = gid >> 9, hc = gid & 511;
    const float* hv = hidden0 + b * 64;
    const float* wv = W_hid + hc * 64;
    float acc = b_hid[hc];
    #pragma unroll
    for (int d = 0; d < 64; d += 4){
      float4 a = *(const float4*)(hv + d);
      float4 w = *(const float4*)(wv + d);
      acc += a.x*w.x + a.y*w.y + a.z*w.z + a.w*w.w;
    }
    out_h0[gid] = acc;          // second output (no relu)
    h0f[gid]    = acc;          // f32 copy for c0
    unsigned short hh, ll; split_f16(acc, hh, ll);
    hf_hi[gid] = hh;            // h buffer 0
    hf_lo[gid] = ll;
  }
  // ---------------- init: x -> f16 hi/lo ----------------
  {
    const float4* x4 = (const float4*)x;
    #pragma unroll
    for (int k = 0; k < 8; ++k){
      int v = gid + k * 16384;              // float4 index, 131072 total
      float4 f = x4[v];
      unsigned short ha,la,hb2,lb2,hc2,lc2,hd,ld;
      split_f16(f.x,ha,la); split_f16(f.y,hb2,lb2);
      split_f16(f.z,hc2,lc2); split_f16(f.w,hd,ld);
      *(ushort4*)(xhi + (size_t)v*4) = make_ushort4(ha,hb2,hc2,hd);
      *(ushort4*)(xlo + (size_t)v*4) = make_ushort4(la,lb2,lc2,ld);
    }
  }

  // global gate row for this lane's A-fragment row m of tile r
  const int R = (r == 0) ? ((m < 8) ? (J0 + m) : (512 + J0 + m - 8))
                         : ((m < 8) ? (1024 + J0 + m) : (1536 + J0 + (m - 8)));

  // ---------------- W_hh fragments -> registers (once) ----------------
  f16x8 whh_hi[16], whh_lo[16];
  #pragma unroll
  for (int kc = 0; kc < 16; ++kc){
    const float* p = W_hh + R * 512 + kc * 32 + g * 8;
    float4 f0 = *(const float4*)p;
    float4 f1 = *(const float4*)(p + 4);
    float fs[8] = {f0.x,f0.y,f0.z,f0.w,f1.x,f1.y,f1.z,f1.w};
    short8 hb, lb;
    #pragma unroll
    for (int i = 0; i < 8; ++i){
      unsigned short hh, ll; split_f16(fs[i], hh, ll);
      hb[i] = (short)hh; lb[i] = (short)ll;
    }
    whh_hi[kc] = __builtin_bit_cast(f16x8, hb);
    whh_lo[kc] = __builtin_bit_cast(f16x8, lb);
  }

  // c-update ownership: thread -> (batch cb, hidden col J0+cj)
  const int cb = tid >> 3;
  const int cj = tid & 7;
  const float bias_i = b_ih[J0+cj]      + b_hh[J0+cj];
  const float bias_f = b_ih[512+J0+cj]  + b_hh[512+J0+cj];
  const float bias_g = b_ih[1024+J0+cj] + b_hh[1024+J0+cj];
  const float bias_o = b_ih[1536+J0+cj] + b_hh[1536+J0+cj];

  // ---------------- grid barrier 0 (init done) ----------------
  __syncthreads();
  if (tid == 0){
    __hip_atomic_fetch_add(&ctr[0], 1u, __ATOMIC_RELEASE, __HIP_MEMORY_SCOPE_AGENT);
    while (__hip_atomic_load(&ctr[0], __ATOMIC_RELAXED, __HIP_MEMORY_SCOPE_AGENT) < (unsigned)NBLK)
      __builtin_amdgcn_s_sleep(1);
    __builtin_amdgcn_fence(__ATOMIC_ACQUIRE, "agent");
  }
  __syncthreads();

  float c_state = h0f[cb * 512 + J0 + cj];

  // persistent x@W_ih prefix-sum accumulators (MFMA C-operand IS the cumsum)
  const int xb = cc * 16 + m;
  f32x4 axc0 = {0.f,0.f,0.f,0.f}, axc1 = axc0, axc2 = axc0;

  auto xpart = [&](int t){
    #pragma unroll
    for (int kc = 0; kc < 2; ++kc){
      const float* p = W_ih + (size_t)R * 16384 + (size_t)t * 64 + kc * 32 + g * 8;
      float4 f0 = *(const float4*)p;
      float4 f1 = *(const float4*)(p + 4);
      float fs[8] = {f0.x,f0.y,f0.z,f0.w,f1.x,f1.y,f1.z,f1.w};
      short8 hb, lb;
      #pragma unroll
      for (int i = 0; i < 8; ++i){
        unsigned short hh, ll; split_f16(fs[i], hh, ll);
        hb[i] = (short)hh; lb[i] = (short)ll;
      }
      f16x8 ahi = __builtin_bit_cast(f16x8, hb);
      f16x8 alo = __builtin_bit_cast(f16x8, lb);
      size_t off = ((size_t)xb * 256 + (size_t)t) * 64 + kc * 32 + g * 8;
      f16x8 bhi = __builtin_bit_cast(f16x8, *(const short8*)(xhi + off));
      f16x8 blo = __builtin_bit_cast(f16x8, *(const short8*)(xlo + off));
      axc0 = __builtin_amdgcn_mfma_f32_16x16x32_f16(ahi, bhi, axc0, 0,0,0);
      axc1 = __builtin_amdgcn_mfma_f32_16x16x32_f16(ahi, blo, axc1, 0,0,0);
      axc2 = __builtin_amdgcn_mfma_f32_16x16x32_f16(alo, bhi, axc2, 0,0,0);
    }
  };
  xpart(0);

  const int bfrag = cc * 16 + m;       // batch row for B-fragments
  const int bb    = bfrag & 7;
  const int bbase = bfrag << 6;        // 16B-unit base of that row in LDS

  for (int t = 0; t < 256; ++t){
    const int pr = t & 1, pw = (t + 1) & 1;

    // ---- stage h(t) global->LDS, pre-swizzled source, linear LDS dest ----
    #pragma unroll
    for (int i = 0; i < 8; ++i){
      int b  = i * 4 + wid;                       // batch row this wave-round
      int su = (b << 6) + (lane ^ (b & 7));       // swizzled source unit
      const unsigned short* srcH = hf_hi + (size_t)pr * 16384 + (size_t)su * 8;
      const unsigned short* srcL = hf_lo + (size_t)pr * 16384 + (size_t)su * 8;
      __builtin_amdgcn_global_load_lds(
        (const __attribute__((address_space(1))) unsigned int*)srcH,
        (__attribute__((address_space(3))) unsigned int*)(hs_hi + (i * 256 + wid * 64) * 8),
        16, 0, 0);
      __builtin_amdgcn_global_load_lds(
        (const __attribute__((address_space(1))) unsigned int*)srcL,
        (__attribute__((address_space(3))) unsigned int*)(hs_lo + (i * 256 + wid * 64) * 8),
        16, 0, 0);
    }
    asm volatile("s_waitcnt vmcnt(0)" ::: "memory");
    __syncthreads();

    // ---- h @ W_hh^T via MFMA, 3-term hi/lo split, 3 parallel acc chains ----
    f32x4 acc0 = {0.f,0.f,0.f,0.f}, acc1 = acc0, acc2 = acc0;
    #pragma unroll
    for (int kc = 0; kc < 16; ++kc){
      int us = ((kc << 2) + g) ^ bb;             // swizzled unit within row
      f16x8 bhi = __builtin_bit_cast(f16x8, *(const short8*)(hs_hi + ((bbase + us) << 3)));
      f16x8 blo = __builtin_bit_cast(f16x8, *(const short8*)(hs_lo + ((bbase + us) << 3)));
      acc0 = __builtin_amdgcn_mfma_f32_16x16x32_f16(whh_hi[kc], bhi, acc0, 0,0,0);
      acc1 = __builtin_amdgcn_mfma_f32_16x16x32_f16(whh_hi[kc], blo, acc1, 0,0,0);
      acc2 = __builtin_amdgcn_mfma_f32_16x16x32_f16(whh_lo[kc], bhi, acc2, 0,0,0);
    }

    // ---- exchange gate pre-activations through LDS ----
    f32x4 tot = acc0 + acc1 + acc2 + axc0 + axc1 + axc2;
    #pragma unroll
    for (int q = 0; q < 4; ++q)
      gs[r * 16 + g * 4 + q][cc * 16 + m] = tot[q];
    __syncthreads();

    // ---- gate nonlinearities + state update (thread owns (cb, cj)) ----
    {
      float pi = gs[cj][cb]      + bias_i;
      float pf = gs[8 + cj][cb]  + bias_f;
      float pg = gs[16 + cj][cb] + bias_g;
      float po = gs[24 + cj][cb] + bias_o;
      float ig = 1.f / (1.f + expf(-pi));
      float fg = 1.f / (1.f + expf(-pf));
      float gg = tanhf(pg);
      float og = 1.f / (1.f + expf(-po));
      c_state = fg * c_state + ig * gg;
      float hval = og * tanhf(c_state);
      out[(size_t)(cb * 256 + t) * 512 + J0 + cj] = fmaxf(hval, 0.f);
      unsigned short hh, ll; split_f16(hval, hh, ll);
      size_t ho = (size_t)pw * 16384 + (size_t)cb * 512 + J0 + cj;
      hf_hi[ho] = hh;
      hf_lo[ho] = ll;
    }

    // ---- grid barrier, with x-part(t+1) overlapped into the wait ----
    if (t < 255){
      __syncthreads();
      if (tid == 0)
        __hip_atomic_fetch_add(&ctr[t + 1], 1u, __ATOMIC_RELEASE, __HIP_MEMORY_SCOPE_AGENT);
      xpart(t + 1);   // independent of h(t+1): hides barrier + HBM latency
      if (tid == 0){
        while (__hip_atomic_load(&ctr[t + 1], __ATOMIC_RELAXED, __HIP_MEMORY_SCOPE_AGENT) < (unsigned)NBLK)
          __builtin_amdgcn_s_sleep(1);
        __builtin_amdgcn_fence(__ATOMIC_ACQUIRE, "agent");
      }
      __syncthreads();
    }
  }
}

// ---------------------------------------------------------------------------
extern "C" void kernel_launch(void* const* d_in, const int* in_sizes, int n_in,
                              void* d_out, int out_size, void* d_ws, size_t ws_size,
                              hipStream_t stream) {
  const float* x       = (const float*)d_in[0];
  const float* hidden0 = (const float*)d_in[1];
  const float* W_hid   = (const float*)d_in[2];
  const float* b_hid   = (const float*)d_in[3];
  const float* W_ih    = (const float*)d_in[4];
  const float* W_hh    = (const float*)d_in[5];
  const float* b_ih    = (const float*)d_in[6];
  const float* b_hh    = (const float*)d_in[7];

  float* out    = (float*)d_out;
  float* out_h0 = out + (size_t)32 * 256 * 512;

  char* ws = (char*)d_ws;
  unsigned*       ctr   = (unsigned*)ws;                       // 2048 B
  float*          h0f   = (float*)(ws + 2048);                 // 64 KB
  unsigned short* hf_hi = (unsigned short*)(ws + 2048 + 65536);          // 64 KB (2 bufs)
  unsigned short* hf_lo = (unsigned short*)(ws + 2048 + 65536 + 65536);  // 64 KB
  unsigned short* xhi   = (unsigned short*)(ws + 2048 + 65536 + 131072);           // 1 MB
  unsigned short* xlo   = (unsigned short*)(ws + 2048 + 65536 + 131072 + 1048576); // 1 MB

  hipMemsetAsync(ctr, 0, 2048, stream);

  lstm_persist<<<NBLK, 256, 0, stream>>>(
      x, hidden0, W_hid, b_hid, W_ih, W_hh, b_ih, b_hh,
      out, out_h0, ctr, h0f, hf_hi, hf_lo, xhi, xlo);
}

// Round 4
// 1116.010 us; speedup vs baseline: 1.8533x; 1.1576x over previous
//
#include <hip/hip_runtime.h>
#include <math.h>

#define NBLK 64

typedef __attribute__((ext_vector_type(8))) short short8;
typedef __attribute__((ext_vector_type(8))) _Float16 f16x8;
typedef __attribute__((ext_vector_type(4))) float f32x4;

__device__ __forceinline__ void split_f16(float f, unsigned short& h, unsigned short& l){
  _Float16 hh = (_Float16)f;
  _Float16 ll = (_Float16)(f - (float)hh);
  h = __builtin_bit_cast(unsigned short, hh);
  l = __builtin_bit_cast(unsigned short, ll);
}

__global__ __launch_bounds__(256, 1) void lstm_persist(
    const float* __restrict__ x,
    const float* __restrict__ hidden0,
    const float* __restrict__ W_hid,
    const float* __restrict__ b_hid,
    const float* __restrict__ W_ih,
    const float* __restrict__ W_hh,
    const float* __restrict__ b_ih,
    const float* __restrict__ b_hh,
    float* __restrict__ out,
    float* __restrict__ out_h0,
    unsigned* __restrict__ flags,         // [64] monotonic step flags
    unsigned short* __restrict__ hf_hi,   // [2][32][512] f16 bits (IF-coherent)
    unsigned short* __restrict__ hf_lo,
    unsigned short* __restrict__ xhi,     // [32][256][64] f16 bits
    unsigned short* __restrict__ xlo)
{
  __shared__ unsigned short hs_hi[16384];  // 32 KB, [32 rows][64 units], XOR-swizzled
  __shared__ unsigned short hs_lo[16384];
  __shared__ float gs[32][33];

  const int tid  = threadIdx.x;
  const int bid  = blockIdx.x;
  const int lane = tid & 63;
  const int wid  = tid >> 6;   // 0..3
  const int r    = wid >> 1;   // 0 = i/f quadrants, 1 = g/o
  const int cc   = wid & 1;    // batch half
  const int m    = lane & 15;
  const int g    = lane >> 4;
  const int J0   = bid * 8;    // this block owns hidden cols J0..J0+7
  const int gid  = bid * 256 + tid;
  const int cb   = tid >> 3;   // owner thread -> (batch cb, col J0+cj)
  const int cj   = tid & 7;

  // ---------------- init: h0 = hidden0 @ W_hid^T + b_hid ----------------
  {
    int b = gid >> 9, hc = gid & 511;
    const float* hv = hidden0 + b * 64;
    const float* wv = W_hid + hc * 64;
    float acc = b_hid[hc];
    #pragma unroll
    for (int d = 0; d < 64; d += 4){
      float4 a = *(const float4*)(hv + d);
      float4 w = *(const float4*)(wv + d);
      acc += a.x*w.x + a.y*w.y + a.z*w.z + a.w*w.w;
    }
    out_h0[gid] = acc;                       // second output
    unsigned short hh, ll; split_f16(acc, hh, ll);
    unsigned vh = hh, vl = ll;
    asm volatile("global_store_short %0, %1, off sc0 sc1" :: "v"(hf_hi + gid), "v"(vh) : "memory");
    asm volatile("global_store_short %0, %1, off sc0 sc1" :: "v"(hf_lo + gid), "v"(vl) : "memory");
  }
  // ---------------- init: x -> f16 hi/lo (write-through) ----------------
  {
    const float4* x4 = (const float4*)x;
    #pragma unroll
    for (int k = 0; k < 8; ++k){
      int v = gid + k * 16384;
      float4 f = x4[v];
      unsigned short ha,la,hb2,lb2,hc2,lc2,hd,ld;
      split_f16(f.x,ha,la); split_f16(f.y,hb2,lb2);
      split_f16(f.z,hc2,lc2); split_f16(f.w,hd,ld);
      uint2 ph, pl;
      ph.x = (unsigned)ha | ((unsigned)hb2 << 16);
      ph.y = (unsigned)hc2 | ((unsigned)hd << 16);
      pl.x = (unsigned)la | ((unsigned)lb2 << 16);
      pl.y = (unsigned)lc2 | ((unsigned)ld << 16);
      asm volatile("global_store_dwordx2 %0, %1, off sc0 sc1" :: "v"(xhi + (size_t)v*4), "v"(ph) : "memory");
      asm volatile("global_store_dwordx2 %0, %1, off sc0 sc1" :: "v"(xlo + (size_t)v*4), "v"(pl) : "memory");
    }
  }
  // ---------------- own c0, exact f32 (no cross-block read) ----------------
  float c_state;
  {
    const float* hv = hidden0 + cb * 64;
    const float* wv = W_hid + (J0 + cj) * 64;
    float acc = b_hid[J0 + cj];
    #pragma unroll
    for (int d = 0; d < 64; d += 4){
      float4 a = *(const float4*)(hv + d);
      float4 w = *(const float4*)(wv + d);
      acc += a.x*w.x + a.y*w.y + a.z*w.z + a.w*w.w;
    }
    c_state = acc;
  }

  // gate row for this lane's A-fragment (quadrant-major)
  const int R = (r == 0) ? ((m < 8) ? (J0 + m) : (512 + J0 + m - 8))
                         : ((m < 8) ? (1024 + J0 + m) : (1536 + J0 + (m - 8)));

  // ---------------- W_hh fragments -> registers (once) ----------------
  f16x8 whh_hi[16], whh_lo[16];
  #pragma unroll
  for (int kc = 0; kc < 16; ++kc){
    const float* p = W_hh + R * 512 + kc * 32 + g * 8;
    float4 f0 = *(const float4*)p;
    float4 f1 = *(const float4*)(p + 4);
    float fs[8] = {f0.x,f0.y,f0.z,f0.w,f1.x,f1.y,f1.z,f1.w};
    short8 hb, lb;
    #pragma unroll
    for (int i = 0; i < 8; ++i){
      unsigned short hh, ll; split_f16(fs[i], hh, ll);
      hb[i] = (short)hh; lb[i] = (short)ll;
    }
    whh_hi[kc] = __builtin_bit_cast(f16x8, hb);
    whh_lo[kc] = __builtin_bit_cast(f16x8, lb);
  }

  const float bias_i = b_ih[J0+cj]      + b_hh[J0+cj];
  const float bias_f = b_ih[512+J0+cj]  + b_hh[512+J0+cj];
  const float bias_g = b_ih[1024+J0+cj] + b_hh[1024+J0+cj];
  const float bias_o = b_ih[1536+J0+cj] + b_hh[1536+J0+cj];

  // ---------------- post init flag (=1) ----------------
  asm volatile("s_waitcnt vmcnt(0)" ::: "memory");
  __syncthreads();
  if (tid == 0){
    unsigned one = 1;
    asm volatile("global_store_dword %0, %1, off sc0 sc1" :: "v"(flags + bid), "v"(one) : "memory");
  }

  // poll: all 64 flags >= v (one lane per flag, coalesced uncached load)
  #define POLL(vtarget)                                                              \
    {                                                                                \
      unsigned _tg = (vtarget);                                                      \
      const unsigned* _fp = flags + lane;                                            \
      while (true){                                                                  \
        unsigned _fv;                                                                \
        asm volatile("global_load_dword %0, %1, off sc0 sc1\n\ts_waitcnt vmcnt(0)"   \
                     : "=v"(_fv) : "v"(_fp) : "memory");                             \
        if (__all((int)(_fv >= _tg))) break;                                         \
        __builtin_amdgcn_s_sleep(1);                                                 \
      }                                                                              \
    }

  // persistent x@W_ih prefix-sum accumulators
  const int xb = cc * 16 + m;
  f32x4 axc0 = {0.f,0.f,0.f,0.f}, axc1 = axc0, axc2 = axc0;

  auto xpart = [&](int t){
    #pragma unroll
    for (int kc = 0; kc < 2; ++kc){
      const float* p = W_ih + (size_t)R * 16384 + (size_t)t * 64 + kc * 32 + g * 8;
      float4 f0 = *(const float4*)p;
      float4 f1 = *(const float4*)(p + 4);
      float fs[8] = {f0.x,f0.y,f0.z,f0.w,f1.x,f1.y,f1.z,f1.w};
      short8 hb, lb;
      #pragma unroll
      for (int i = 0; i < 8; ++i){
        unsigned short hh, ll; split_f16(fs[i], hh, ll);
        hb[i] = (short)hh; lb[i] = (short)ll;
      }
      f16x8 ahi = __builtin_bit_cast(f16x8, hb);
      f16x8 alo = __builtin_bit_cast(f16x8, lb);
      size_t off = ((size_t)xb * 256 + (size_t)t) * 64 + kc * 32 + g * 8;
      f16x8 bhi = __builtin_bit_cast(f16x8, *(const short8*)(xhi + off));
      f16x8 blo = __builtin_bit_cast(f16x8, *(const short8*)(xlo + off));
      axc0 = __builtin_amdgcn_mfma_f32_16x16x32_f16(ahi, bhi, axc0, 0,0,0);
      axc1 = __builtin_amdgcn_mfma_f32_16x16x32_f16(ahi, blo, axc1, 0,0,0);
      axc2 = __builtin_amdgcn_mfma_f32_16x16x32_f16(alo, bhi, axc2, 0,0,0);
    }
  };

  POLL(1u);
  xpart(0);

  const int bfrag = cc * 16 + m;
  const int bb    = bfrag & 7;
  const int bbase = bfrag << 6;        // 16B-unit base of B-frag row

  for (int t = 0; t < 256; ++t){
    const int pr = t & 1, pw = (t + 1) & 1;

    POLL((unsigned)(t + 1));

    // ---- stage h(t): 16 uncached dwordx4 loads -> swizzled ds_write_b128 ----
    {
      uint4 th[8], tl[8];
      const unsigned short* hbH = hf_hi + (size_t)pr * 16384;
      const unsigned short* hbL = hf_lo + (size_t)pr * 16384;
      #pragma unroll
      for (int k = 0; k < 8; ++k){
        asm volatile("global_load_dwordx4 %0, %1, off sc0 sc1"
                     : "=v"(th[k]) : "v"(hbH + (size_t)(tid + k*256) * 8));
        asm volatile("global_load_dwordx4 %0, %1, off sc0 sc1"
                     : "=v"(tl[k]) : "v"(hbL + (size_t)(tid + k*256) * 8));
      }
      // rule-#18 idiom: bare waitcnt + memory clobber, then sched_barrier(0)
      // so the dependent ds_writes can't be hoisted above the wait.
      asm volatile("s_waitcnt vmcnt(0)" ::: "memory");
      __builtin_amdgcn_sched_barrier(0);
      #pragma unroll
      for (int k = 0; k < 8; ++k){
        int U = tid + k * 256;               // 16B unit 0..2047
        int b = U >> 6, u = U & 63;
        int us = u ^ (b & 7);
        *(uint4*)(hs_hi + (size_t)((b << 6) + us) * 8) = th[k];
        *(uint4*)(hs_lo + (size_t)((b << 6) + us) * 8) = tl[k];
      }
    }
    __syncthreads();

    // ---- h @ W_hh^T via MFMA, 3-term hi/lo split ----
    f32x4 acc0 = {0.f,0.f,0.f,0.f}, acc1 = acc0, acc2 = acc0;
    #pragma unroll
    for (int kc = 0; kc < 16; ++kc){
      int us = ((kc << 2) + g) ^ bb;
      f16x8 bhi = __builtin_bit_cast(f16x8, *(const short8*)(hs_hi + ((bbase + us) << 3)));
      f16x8 blo = __builtin_bit_cast(f16x8, *(const short8*)(hs_lo + ((bbase + us) << 3)));
      acc0 = __builtin_amdgcn_mfma_f32_16x16x32_f16(whh_hi[kc], bhi, acc0, 0,0,0);
      acc1 = __builtin_amdgcn_mfma_f32_16x16x32_f16(whh_hi[kc], blo, acc1, 0,0,0);
      acc2 = __builtin_amdgcn_mfma_f32_16x16x32_f16(whh_lo[kc], bhi, acc2, 0,0,0);
    }

    // ---- exchange gate pre-activations through LDS ----
    f32x4 tot = acc0 + acc1 + acc2 + axc0 + axc1 + axc2;
    #pragma unroll
    for (int q = 0; q < 4; ++q)
      gs[r * 16 + g * 4 + q][cc * 16 + m] = tot[q];
    __syncthreads();

    // ---- gates + state update; write h(t+1) write-through ----
    {
      float pi = gs[cj][cb]      + bias_i;
      float pf = gs[8 + cj][cb]  + bias_f;
      float pg = gs[16 + cj][cb] + bias_g;
      float po = gs[24 + cj][cb] + bias_o;
      float ig = 1.f / (1.f + expf(-pi));
      float fg = 1.f / (1.f + expf(-pf));
      float gg = tanhf(pg);
      float og = 1.f / (1.f + expf(-po));
      c_state = fg * c_state + ig * gg;
      float hval = og * tanhf(c_state);
      out[(size_t)(cb * 256 + t) * 512 + J0 + cj] = fmaxf(hval, 0.f);
      unsigned short hh, ll; split_f16(hval, hh, ll);
      size_t ho = (size_t)pw * 16384 + (size_t)cb * 512 + J0 + cj;
      unsigned vh = hh, vl = ll;
      asm volatile("global_store_short %0, %1, off sc0 sc1" :: "v"(hf_hi + ho), "v"(vh) : "memory");
      asm volatile("global_store_short %0, %1, off sc0 sc1" :: "v"(hf_lo + ho), "v"(vl) : "memory");
    }

    asm volatile("s_waitcnt vmcnt(0)" ::: "memory");
    __syncthreads();   // all waves' h stores drained before flag post

    if (t < 255){
      if (tid == 0){
        unsigned fv = (unsigned)(t + 2);
        asm volatile("global_store_dword %0, %1, off sc0 sc1" :: "v"(flags + bid), "v"(fv) : "memory");
      }
      xpart(t + 1);    // overlap W_ih streaming + cumsum MFMA into the wait
    }
  }
  #undef POLL
}

// ---------------------------------------------------------------------------
extern "C" void kernel_launch(void* const* d_in, const int* in_sizes, int n_in,
                              void* d_out, int out_size, void* d_ws, size_t ws_size,
                              hipStream_t stream) {
  const float* x       = (const float*)d_in[0];
  const float* hidden0 = (const float*)d_in[1];
  const float* W_hid   = (const float*)d_in[2];
  const float* b_hid   = (const float*)d_in[3];
  const float* W_ih    = (const float*)d_in[4];
  const float* W_hh    = (const float*)d_in[5];
  const float* b_ih    = (const float*)d_in[6];
  const float* b_hh    = (const float*)d_in[7];

  float* out    = (float*)d_out;
  float* out_h0 = out + (size_t)32 * 256 * 512;

  char* ws = (char*)d_ws;
  unsigned*       flags = (unsigned*)ws;                                  // 256 B
  unsigned short* hf_hi = (unsigned short*)(ws + 1024);                   // 64 KB (2 bufs)
  unsigned short* hf_lo = (unsigned short*)(ws + 1024 + 65536);           // 64 KB
  unsigned short* xhi   = (unsigned short*)(ws + 1024 + 131072);          // 1 MB
  unsigned short* xlo   = (unsigned short*)(ws + 1024 + 131072 + 1048576);// 1 MB

  (void)hipMemsetAsync(flags, 0, 256, stream);

  lstm_persist<<<NBLK, 256, 0, stream>>>(
      x, hidden0, W_hid, b_hid, W_ih, W_hh, b_ih, b_hh,
      out, out_h0, flags, hf_hi, hf_lo, xhi, xlo);
}

// Round 5
// 1059.765 us; speedup vs baseline: 1.9516x; 1.0531x over previous
//
#include <hip/hip_runtime.h>
#include <math.h>

#define NBLK 64

typedef __attribute__((ext_vector_type(8))) short short8;
typedef __attribute__((ext_vector_type(8))) _Float16 f16x8;
typedef __attribute__((ext_vector_type(4))) float f32x4;

__device__ __forceinline__ void split_f16(float f, unsigned short& h, unsigned short& l){
  _Float16 hh = (_Float16)f;
  _Float16 ll = (_Float16)(f - (float)hh);
  h = __builtin_bit_cast(unsigned short, hh);
  l = __builtin_bit_cast(unsigned short, ll);
}

__global__ __launch_bounds__(256, 1) void lstm_persist(
    const float* __restrict__ x,
    const float* __restrict__ hidden0,
    const float* __restrict__ W_hid,
    const float* __restrict__ b_hid,
    const float* __restrict__ W_ih,
    const float* __restrict__ W_hh,
    const float* __restrict__ b_ih,
    const float* __restrict__ b_hh,
    float* __restrict__ out,
    float* __restrict__ out_h0,
    unsigned* __restrict__ flags,     // [64] one-time x-init barrier
    unsigned* __restrict__ hsteps,    // [256][32][512] packed (hi16|lo16), 0xFFFFFFFF = not yet
    unsigned short* __restrict__ xhi, // [32][256][64] f16 bits
    unsigned short* __restrict__ xlo)
{
  __shared__ unsigned short hs_hi[16384];  // [32 rows][64 units of 16B], XOR-swizzled
  __shared__ unsigned short hs_lo[16384];
  __shared__ float gs[32][33];

  const int tid  = threadIdx.x;
  const int bid  = blockIdx.x;
  const int lane = tid & 63;
  const int wid  = tid >> 6;   // 0..3
  const int r    = wid >> 1;   // 0 = i/f quadrants, 1 = g/o
  const int cc   = wid & 1;    // batch half
  const int m    = lane & 15;
  const int g    = lane >> 4;
  const int J0   = bid * 8;    // block owns hidden cols J0..J0+7
  const int gid  = bid * 256 + tid;
  const int cb   = tid >> 3;   // owner thread -> (batch cb, col J0+cj)
  const int cj   = tid & 7;

  // ---------------- init: h0 = hidden0 @ W_hid^T + b_hid ----------------
  {
    int b = gid >> 9, hc = gid & 511;
    const float* hv = hidden0 + b * 64;
    const float* wv = W_hid + hc * 64;
    float acc = b_hid[hc];
    #pragma unroll
    for (int d = 0; d < 64; d += 4){
      float4 a = *(const float4*)(hv + d);
      float4 w = *(const float4*)(wv + d);
      acc += a.x*w.x + a.y*w.y + a.z*w.z + a.w*w.w;
    }
    out_h0[gid] = acc;                       // second output
    unsigned short hh, ll; split_f16(acc, hh, ll);
    unsigned packed = ((unsigned)hh << 16) | (unsigned)ll;
    asm volatile("global_store_dword %0, %1, off sc0 sc1" :: "v"(hsteps + gid), "v"(packed) : "memory");
  }
  // ---------------- init: x -> f16 hi/lo (write-through) ----------------
  {
    const float4* x4 = (const float4*)x;
    #pragma unroll
    for (int k = 0; k < 8; ++k){
      int v = gid + k * 16384;
      float4 f = x4[v];
      unsigned short ha,la,hb2,lb2,hc2,lc2,hd,ld;
      split_f16(f.x,ha,la); split_f16(f.y,hb2,lb2);
      split_f16(f.z,hc2,lc2); split_f16(f.w,hd,ld);
      uint2 ph, pl;
      ph.x = (unsigned)ha | ((unsigned)hb2 << 16);
      ph.y = (unsigned)hc2 | ((unsigned)hd << 16);
      pl.x = (unsigned)la | ((unsigned)lb2 << 16);
      pl.y = (unsigned)lc2 | ((unsigned)ld << 16);
      asm volatile("global_store_dwordx2 %0, %1, off sc0 sc1" :: "v"(xhi + (size_t)v*4), "v"(ph) : "memory");
      asm volatile("global_store_dwordx2 %0, %1, off sc0 sc1" :: "v"(xlo + (size_t)v*4), "v"(pl) : "memory");
    }
  }
  // ---------------- own c0, exact f32 ----------------
  float c_state;
  {
    const float* hv = hidden0 + cb * 64;
    const float* wv = W_hid + (J0 + cj) * 64;
    float acc = b_hid[J0 + cj];
    #pragma unroll
    for (int d = 0; d < 64; d += 4){
      float4 a = *(const float4*)(hv + d);
      float4 w = *(const float4*)(wv + d);
      acc += a.x*w.x + a.y*w.y + a.z*w.z + a.w*w.w;
    }
    c_state = acc;
  }

  // gate row for this lane's A-fragment (quadrant-major)
  const int R = (r == 0) ? ((m < 8) ? (J0 + m) : (512 + J0 + m - 8))
                         : ((m < 8) ? (1024 + J0 + m) : (1536 + J0 + (m - 8)));

  // ---------------- W_hh fragments -> registers (once) ----------------
  f16x8 whh_hi[16], whh_lo[16];
  #pragma unroll
  for (int kc = 0; kc < 16; ++kc){
    const float* p = W_hh + R * 512 + kc * 32 + g * 8;
    float4 f0 = *(const float4*)p;
    float4 f1 = *(const float4*)(p + 4);
    float fs[8] = {f0.x,f0.y,f0.z,f0.w,f1.x,f1.y,f1.z,f1.w};
    short8 hb, lb;
    #pragma unroll
    for (int i = 0; i < 8; ++i){
      unsigned short hh, ll; split_f16(fs[i], hh, ll);
      hb[i] = (short)hh; lb[i] = (short)ll;
    }
    whh_hi[kc] = __builtin_bit_cast(f16x8, hb);
    whh_lo[kc] = __builtin_bit_cast(f16x8, lb);
  }

  const float bias_i = b_ih[J0+cj]      + b_hh[J0+cj];
  const float bias_f = b_ih[512+J0+cj]  + b_hh[512+J0+cj];
  const float bias_g = b_ih[1024+J0+cj] + b_hh[1024+J0+cj];
  const float bias_o = b_ih[1536+J0+cj] + b_hh[1536+J0+cj];

  // ---------------- one-time barrier: x f16 conversion complete ----------------
  asm volatile("s_waitcnt vmcnt(0)" ::: "memory");
  __syncthreads();
  if (tid == 0){
    unsigned one = 1;
    asm volatile("global_store_dword %0, %1, off sc0 sc1" :: "v"(flags + bid), "v"(one) : "memory");
  }
  {
    const unsigned* fp = flags + lane;
    while (true){
      unsigned fv;
      asm volatile("global_load_dword %0, %1, off sc0 sc1\n\ts_waitcnt vmcnt(0)"
                   : "=v"(fv) : "v"(fp) : "memory");
      if (__all((int)(fv >= 1u))) break;
      __builtin_amdgcn_s_sleep(1);
    }
  }

  // persistent x@W_ih prefix-sum accumulators
  const int xb = cc * 16 + m;
  f32x4 axc0 = {0.f,0.f,0.f,0.f}, axc1 = axc0, axc2 = axc0;

  auto xpart = [&](int t){
    #pragma unroll
    for (int kc = 0; kc < 2; ++kc){
      const float* p = W_ih + (size_t)R * 16384 + (size_t)t * 64 + kc * 32 + g * 8;
      float4 f0 = *(const float4*)p;
      float4 f1 = *(const float4*)(p + 4);
      float fs[8] = {f0.x,f0.y,f0.z,f0.w,f1.x,f1.y,f1.z,f1.w};
      short8 hb, lb;
      #pragma unroll
      for (int i = 0; i < 8; ++i){
        unsigned short hh, ll; split_f16(fs[i], hh, ll);
        hb[i] = (short)hh; lb[i] = (short)ll;
      }
      f16x8 ahi = __builtin_bit_cast(f16x8, hb);
      f16x8 alo = __builtin_bit_cast(f16x8, lb);
      size_t off = ((size_t)xb * 256 + (size_t)t) * 64 + kc * 32 + g * 8;
      f16x8 bhi = __builtin_bit_cast(f16x8, *(const short8*)(xhi + off));
      f16x8 blo = __builtin_bit_cast(f16x8, *(const short8*)(xlo + off));
      axc0 = __builtin_amdgcn_mfma_f32_16x16x32_f16(ahi, bhi, axc0, 0,0,0);
      axc1 = __builtin_amdgcn_mfma_f32_16x16x32_f16(ahi, blo, axc1, 0,0,0);
      axc2 = __builtin_amdgcn_mfma_f32_16x16x32_f16(alo, bhi, axc2, 0,0,0);
    }
  };
  xpart(0);

  const int bfrag = cc * 16 + m;
  const int bb    = bfrag & 7;
  const int bbase = bfrag << 6;        // 16B-unit base of B-frag row

  for (int t = 0; t < 256; ++t){
    // ---- self-announcing h(t) load: poll until no dword is sentinel ----
    {
      uint4 d[16];
      const unsigned* hb = hsteps + (size_t)t * 16384;
      while (true){
        #pragma unroll
        for (int k = 0; k < 8; ++k){
          const unsigned* p = hb + (size_t)(tid + k*256) * 8;
          asm volatile("global_load_dwordx4 %0, %1, off sc0 sc1" : "=v"(d[2*k])   : "v"(p));
          asm volatile("global_load_dwordx4 %0, %1, off sc0 sc1" : "=v"(d[2*k+1]) : "v"(p+4));
        }
        asm volatile("s_waitcnt vmcnt(0)" ::: "memory");
        __builtin_amdgcn_sched_barrier(0);
        unsigned mx = 0u;
        #pragma unroll
        for (int k = 0; k < 16; ++k){
          unsigned a  = d[k].x > d[k].y ? d[k].x : d[k].y;
          unsigned b2 = d[k].z > d[k].w ? d[k].z : d[k].w;
          unsigned c2 = a > b2 ? a : b2;
          mx = mx > c2 ? mx : c2;
        }
        if (__all((int)(mx != 0xFFFFFFFFu))) break;   // sentinel impossible in valid data
        __builtin_amdgcn_s_sleep(1);
      }
      // ---- unpack hi/lo + swizzled LDS write ----
      #pragma unroll
      for (int k = 0; k < 8; ++k){
        int P = tid + k * 256;            // pair-unit: 8 dwords = 8 h elements
        int b = P >> 6, u = P & 63;
        int us = u ^ (b & 7);
        uint4 d0 = d[2*k], d1 = d[2*k+1];
        uint4 hi4, lo4;
        hi4.x = (d0.x >> 16) | (d0.y & 0xFFFF0000u);
        hi4.y = (d0.z >> 16) | (d0.w & 0xFFFF0000u);
        hi4.z = (d1.x >> 16) | (d1.y & 0xFFFF0000u);
        hi4.w = (d1.z >> 16) | (d1.w & 0xFFFF0000u);
        lo4.x = (d0.x & 0xFFFFu) | (d0.y << 16);
        lo4.y = (d0.z & 0xFFFFu) | (d0.w << 16);
        lo4.z = (d1.x & 0xFFFFu) | (d1.y << 16);
        lo4.w = (d1.z & 0xFFFFu) | (d1.w << 16);
        *(uint4*)(hs_hi + (size_t)((b << 6) + us) * 8) = hi4;
        *(uint4*)(hs_lo + (size_t)((b << 6) + us) * 8) = lo4;
      }
    }
    __syncthreads();

    // ---- h @ W_hh^T via MFMA, 3-term hi/lo split ----
    f32x4 acc0 = {0.f,0.f,0.f,0.f}, acc1 = acc0, acc2 = acc0;
    #pragma unroll
    for (int kc = 0; kc < 16; ++kc){
      int us = ((kc << 2) + g) ^ bb;
      f16x8 bhi = __builtin_bit_cast(f16x8, *(const short8*)(hs_hi + ((bbase + us) << 3)));
      f16x8 blo = __builtin_bit_cast(f16x8, *(const short8*)(hs_lo + ((bbase + us) << 3)));
      acc0 = __builtin_amdgcn_mfma_f32_16x16x32_f16(whh_hi[kc], bhi, acc0, 0,0,0);
      acc1 = __builtin_amdgcn_mfma_f32_16x16x32_f16(whh_hi[kc], blo, acc1, 0,0,0);
      acc2 = __builtin_amdgcn_mfma_f32_16x16x32_f16(whh_lo[kc], bhi, acc2, 0,0,0);
    }

    // ---- exchange gate pre-activations through LDS ----
    f32x4 tot = acc0 + acc1 + acc2 + axc0 + axc1 + axc2;
    #pragma unroll
    for (int q = 0; q < 4; ++q)
      gs[r * 16 + g * 4 + q][cc * 16 + m] = tot[q];
    __syncthreads();

    // ---- gates + state update; h(t+1) store is fire-and-forget ----
    {
      float pi = gs[cj][cb]      + bias_i;
      float pf = gs[8 + cj][cb]  + bias_f;
      float pg = gs[16 + cj][cb] + bias_g;
      float po = gs[24 + cj][cb] + bias_o;
      float ig = 1.f / (1.f + expf(-pi));
      float fg = 1.f / (1.f + expf(-pf));
      float gg = tanhf(pg);
      float og = 1.f / (1.f + expf(-po));
      c_state = fg * c_state + ig * gg;
      float hval = og * tanhf(c_state);
      if (t < 255){
        unsigned short hh, ll; split_f16(hval, hh, ll);
        unsigned packed = ((unsigned)hh << 16) | (unsigned)ll;   // hi16 never 0xFFFF (|h|<1)
        asm volatile("global_store_dword %0, %1, off sc0 sc1"
                     :: "v"(hsteps + (size_t)(t+1)*16384 + (size_t)cb*512 + J0 + cj), "v"(packed) : "memory");
      }
      out[(size_t)(cb * 256 + t) * 512 + J0 + cj] = fmaxf(hval, 0.f);
    }

    if (t < 255) xpart(t + 1);   // overlap W_ih stream + cumsum MFMA with store latency
  }
}

// ---------------------------------------------------------------------------
extern "C" void kernel_launch(void* const* d_in, const int* in_sizes, int n_in,
                              void* d_out, int out_size, void* d_ws, size_t ws_size,
                              hipStream_t stream) {
  const float* x       = (const float*)d_in[0];
  const float* hidden0 = (const float*)d_in[1];
  const float* W_hid   = (const float*)d_in[2];
  const float* b_hid   = (const float*)d_in[3];
  const float* W_ih    = (const float*)d_in[4];
  const float* W_hh    = (const float*)d_in[5];
  const float* b_ih    = (const float*)d_in[6];
  const float* b_hh    = (const float*)d_in[7];

  float* out    = (float*)d_out;
  float* out_h0 = out + (size_t)32 * 256 * 512;

  char* ws = (char*)d_ws;
  unsigned*       flags  = (unsigned*)ws;                          // 256 B
  unsigned short* xhi    = (unsigned short*)(ws + 4096);           // 1 MB
  unsigned short* xlo    = (unsigned short*)(ws + 4096 + (1<<20)); // 1 MB
  unsigned*       hsteps = (unsigned*)(ws + 4096 + (2<<20));       // 16 MB: [256][32][512] dwords

  (void)hipMemsetAsync(flags, 0, 256, stream);
  (void)hipMemsetAsync(hsteps, 0xFF, (size_t)256 * 16384 * 4, stream);  // sentinel

  lstm_persist<<<NBLK, 256, 0, stream>>>(
      x, hidden0, W_hid, b_hid, W_ih, W_hh, b_ih, b_hh,
      out, out_h0, flags, hsteps, xhi, xlo);
}